// Round 1
// baseline (13785.092 us; speedup 1.0000x reference)
//
#include <hip/hip_runtime.h>
#include <math.h>

static constexpr int V  = 1024;
static constexpr int NH = 256;
static constexpr int B  = 128;
static constexpr int T  = 512;
static constexpr size_t YSZ = (size_t)T * B * V;   // 67,108,864

// d_out layout (f32): y[T*B][V], then H1[B][NH], C1, H2, C2.
// During the recurrence we stash:
//   h2(t) -> y[t*B+b][0:256]        (consumed by final GEMM, then overwritten)
//   h1(t) -> y[t*B+b][256:512]      (scratch, overwritten by final GEMM)
//   c1    -> tail C1 region (in-place), c2 -> tail C2 region.

// ---------------- device cell functions ----------------
// Block = 256 threads: tj = tid&7 (feature within 8-wide slice),
// g2 = (tid>>3)&1 (gate pair: 0 -> f,i ; 1 -> o,c), r = tid>>4 (row 0..15).
// Grid mapping per 256-block stage: p = bid&7 (batch group of 16), f = bid>>3 (32 j-groups of 8).

__device__ __forceinline__ void dev_cell1(
    int bid, int tid, int t,
    const int* __restrict__ X,
    const float* __restrict__ h1prev, int h1s,
    float* __restrict__ c1,
    const float* __restrict__ Wf, const float* __restrict__ bf,
    const float* __restrict__ Wi, const float* __restrict__ bi,
    const float* __restrict__ Wo, const float* __restrict__ bo,
    const float* __restrict__ Wc, const float* __restrict__ bc,
    float* __restrict__ hout,     // row stride V, col offset pre-applied
    float* smem)
{
    float (*sh)[NH + 1] = (float(*)[NH + 1])smem;
    float (*sg)[8][4]   = (float(*)[8][4])(smem + 16 * (NH + 1));
    const int p  = bid & 7;
    const int fI = bid >> 3;
    const int b0 = p * 16;
    const int j0 = fI * 8;

    for (int idx = tid; idx < 16 * NH; idx += 256) {
        int r = idx >> 8, k = idx & 255;
        sh[r][k] = h1prev[(size_t)(b0 + r) * h1s + k];
    }
    __syncthreads();

    const int tj = tid & 7;
    const int g2 = (tid >> 3) & 1;
    const int r  = tid >> 4;
    const int b  = b0 + r;
    const int j  = j0 + tj;
    const int tok = X[b * T + t];

    const float* WA = g2 ? Wo : Wf;
    const float* WB = g2 ? Wc : Wi;
    float accA = (g2 ? bo : bf)[j] + WA[(size_t)tok * NH + j];
    float accB = (g2 ? bc : bi)[j] + WB[(size_t)tok * NH + j];
    const float* wa = WA + (size_t)V * NH + j;
    const float* wb = WB + (size_t)V * NH + j;
    #pragma unroll 8
    for (int k = 0; k < NH; ++k) {
        float h = sh[r][k];
        accA = fmaf(h, wa[(size_t)k * NH], accA);
        accB = fmaf(h, wb[(size_t)k * NH], accB);
    }
    sg[r][tj][g2 * 2 + 0] = accA;
    sg[r][tj][g2 * 2 + 1] = accB;
    __syncthreads();
    if (g2 == 0) {
        float pf = sg[r][tj][0], pi = sg[r][tj][1];
        float po = sg[r][tj][2], pc = sg[r][tj][3];
        float fg = 1.f / (1.f + expf(-pf));
        float ig = 1.f / (1.f + expf(-pi));
        float og = 1.f / (1.f + expf(-po));
        float ct = tanhf(pc);
        float cold = c1[b * NH + j];
        float cn = fmaf(fg, cold, ig * ct);
        c1[b * NH + j] = cn;
        hout[(size_t)b * V + j] = og * tanhf(cn);
    }
}

__device__ __forceinline__ void dev_cell2(
    int bid, int tid,
    const float* __restrict__ h1cur, int h1s,
    const float* __restrict__ h2prev, int h2s,
    float* __restrict__ c2,
    const float* __restrict__ Wf, const float* __restrict__ bf,
    const float* __restrict__ Wi, const float* __restrict__ bi,
    const float* __restrict__ Wo, const float* __restrict__ bo,
    const float* __restrict__ Wc, const float* __restrict__ bc,
    float* __restrict__ hout,
    float* smem)
{
    float (*s1)[NH + 1] = (float(*)[NH + 1])smem;
    float (*s2)[NH + 1] = (float(*)[NH + 1])(smem + 16 * (NH + 1));
    float (*sg)[8][4]   = (float(*)[8][4])(smem + 2 * 16 * (NH + 1));
    const int p  = bid & 7;
    const int fI = bid >> 3;
    const int b0 = p * 16;
    const int j0 = fI * 8;

    for (int idx = tid; idx < 2 * 16 * NH; idx += 256) {
        int which = idx >> 12;
        int r = (idx >> 8) & 15, k = idx & 255;
        float v = which ? h2prev[(size_t)(b0 + r) * h2s + k]
                        : h1cur [(size_t)(b0 + r) * h1s + k];
        if (which) s2[r][k] = v; else s1[r][k] = v;
    }
    __syncthreads();

    const int tj = tid & 7;
    const int g2 = (tid >> 3) & 1;
    const int r  = tid >> 4;
    const int b  = b0 + r;
    const int j  = j0 + tj;

    const float* WA = g2 ? Wo : Wf;
    const float* WB = g2 ? Wc : Wi;
    float accA = (g2 ? bo : bf)[j];
    float accB = (g2 ? bc : bi)[j];
    const float* wa = WA + j;
    const float* wb = WB + j;
    #pragma unroll 8
    for (int k = 0; k < NH; ++k) {
        float h = s1[r][k];
        accA = fmaf(h, wa[(size_t)k * NH], accA);
        accB = fmaf(h, wb[(size_t)k * NH], accB);
    }
    const float* wa2 = WA + (size_t)NH * NH + j;
    const float* wb2 = WB + (size_t)NH * NH + j;
    #pragma unroll 8
    for (int k = 0; k < NH; ++k) {
        float h = s2[r][k];
        accA = fmaf(h, wa2[(size_t)k * NH], accA);
        accB = fmaf(h, wb2[(size_t)k * NH], accB);
    }
    sg[r][tj][g2 * 2 + 0] = accA;
    sg[r][tj][g2 * 2 + 1] = accB;
    __syncthreads();
    if (g2 == 0) {
        float pf = sg[r][tj][0], pi = sg[r][tj][1];
        float po = sg[r][tj][2], pc = sg[r][tj][3];
        float fg = 1.f / (1.f + expf(-pf));
        float ig = 1.f / (1.f + expf(-pi));
        float og = 1.f / (1.f + expf(-po));
        float ct = tanhf(pc);
        float cold = c2[b * NH + j];
        float cn = fmaf(fg, cold, ig * ct);
        c2[b * NH + j] = cn;
        hout[(size_t)b * V + j] = og * tanhf(cn);
    }
}

// ---------------- global kernels ----------------

__global__ __launch_bounds__(256) void k_init(
    const float* __restrict__ C1in, const float* __restrict__ C2in,
    float* __restrict__ c1, float* __restrict__ c2)
{
    int i = blockIdx.x * 256 + threadIdx.x;   // 32768
    c1[i] = C1in[i];
    c2[i] = C2in[i];
}

__global__ __launch_bounds__(256) void k_cell1_first(
    const int* __restrict__ X,
    const float* __restrict__ H1in,
    float* __restrict__ c1,
    const float* __restrict__ W1f, const float* __restrict__ b1f,
    const float* __restrict__ W1i, const float* __restrict__ b1i,
    const float* __restrict__ W1o, const float* __restrict__ b1o,
    const float* __restrict__ W1c, const float* __restrict__ b1c,
    float* __restrict__ hout)
{
    __shared__ float smem[16 * (NH + 1) + 16 * 8 * 4];
    dev_cell1(blockIdx.x, threadIdx.x, 0, X, H1in, NH, c1,
              W1f, b1f, W1i, b1i, W1o, b1o, W1c, b1c, hout, smem);
}

// step t: blocks [0,256) do cell2(t); blocks [256,512) do cell1(t+1)
__global__ __launch_bounds__(256) void k_step(
    int t, const int* __restrict__ X,
    const float* __restrict__ h2prev, int h2s,
    float* __restrict__ y,
    float* __restrict__ c1, float* __restrict__ c2,
    const float* __restrict__ W1f, const float* __restrict__ b1f,
    const float* __restrict__ W1i, const float* __restrict__ b1i,
    const float* __restrict__ W1o, const float* __restrict__ b1o,
    const float* __restrict__ W1c, const float* __restrict__ b1c,
    const float* __restrict__ W2f, const float* __restrict__ b2f,
    const float* __restrict__ W2i, const float* __restrict__ b2i,
    const float* __restrict__ W2o, const float* __restrict__ b2o,
    const float* __restrict__ W2c, const float* __restrict__ b2c)
{
    __shared__ float smem[2 * 16 * (NH + 1) + 16 * 8 * 4];
    const float* h1cur = y + (size_t)t * B * V + NH;
    if (blockIdx.x < 256) {
        dev_cell2(blockIdx.x, threadIdx.x, h1cur, V, h2prev, h2s, c2,
                  W2f, b2f, W2i, b2i, W2o, b2o, W2c, b2c,
                  y + (size_t)t * B * V, smem);
    } else {
        dev_cell1(blockIdx.x - 256, threadIdx.x, t + 1, X, h1cur, V, c1,
                  W1f, b1f, W1i, b1i, W1o, b1o, W1c, b1c,
                  y + (size_t)(t + 1) * B * V + NH, smem);
    }
}

__global__ __launch_bounds__(256) void k_cell2_last(
    const float* __restrict__ h1cur,
    const float* __restrict__ h2prev,
    float* __restrict__ c2,
    const float* __restrict__ W2f, const float* __restrict__ b2f,
    const float* __restrict__ W2i, const float* __restrict__ b2i,
    const float* __restrict__ W2o, const float* __restrict__ b2o,
    const float* __restrict__ W2c, const float* __restrict__ b2c,
    float* __restrict__ hout)
{
    __shared__ float smem[2 * 16 * (NH + 1) + 16 * 8 * 4];
    dev_cell2(blockIdx.x, threadIdx.x, h1cur, V, h2prev, V, c2,
              W2f, b2f, W2i, b2i, W2o, b2o, W2c, b2c, hout, smem);
}

__global__ __launch_bounds__(256) void k_states(
    const float* __restrict__ y, float* __restrict__ H1t, float* __restrict__ H2t)
{
    int i = blockIdx.x * 256 + threadIdx.x;   // 32768
    int b = i >> 8, j = i & 255;
    H1t[i] = y[(size_t)((T - 1) * B + b) * V + NH + j];
    H2t[i] = y[(size_t)((T - 1) * B + b) * V + j];
}

// Y = H2_all @ Wout + bout, in place: h2 stored in y[m][0:256]
__global__ __launch_bounds__(256) void k_ygemm(
    float* __restrict__ y, const float* __restrict__ Wout, const float* __restrict__ bout)
{
    __shared__ float sh[32][NH];
    const size_t m0 = (size_t)blockIdx.x * 32;
    for (int idx = threadIdx.x; idx < 32 * NH; idx += 256) {
        int r = idx >> 8, k = idx & 255;
        sh[r][k] = y[(m0 + r) * V + k];
    }
    __syncthreads();
    const int tr = threadIdx.x >> 6;   // 0..3 (one value per wave)
    const int tc = threadIdx.x & 63;
    for (int mb = 0; mb < 2; ++mb) {
        const int r0 = mb * 16 + tr * 4;
        for (int nb = 0; nb < 4; ++nb) {
            const int n0 = nb * 256 + tc * 4;
            float4 a0 = {0.f,0.f,0.f,0.f}, a1 = a0, a2 = a0, a3 = a0;
            #pragma unroll 4
            for (int k = 0; k < NH; ++k) {
                const float4 w = *(const float4*)&Wout[(size_t)k * V + n0];
                const float h0 = sh[r0 + 0][k];
                const float h1 = sh[r0 + 1][k];
                const float h2 = sh[r0 + 2][k];
                const float h3 = sh[r0 + 3][k];
                a0.x = fmaf(h0, w.x, a0.x); a0.y = fmaf(h0, w.y, a0.y);
                a0.z = fmaf(h0, w.z, a0.z); a0.w = fmaf(h0, w.w, a0.w);
                a1.x = fmaf(h1, w.x, a1.x); a1.y = fmaf(h1, w.y, a1.y);
                a1.z = fmaf(h1, w.z, a1.z); a1.w = fmaf(h1, w.w, a1.w);
                a2.x = fmaf(h2, w.x, a2.x); a2.y = fmaf(h2, w.y, a2.y);
                a2.z = fmaf(h2, w.z, a2.z); a2.w = fmaf(h2, w.w, a2.w);
                a3.x = fmaf(h3, w.x, a3.x); a3.y = fmaf(h3, w.y, a3.y);
                a3.z = fmaf(h3, w.z, a3.z); a3.w = fmaf(h3, w.w, a3.w);
            }
            const float4 bb = *(const float4*)&bout[n0];
            a0.x += bb.x; a0.y += bb.y; a0.z += bb.z; a0.w += bb.w;
            a1.x += bb.x; a1.y += bb.y; a1.z += bb.z; a1.w += bb.w;
            a2.x += bb.x; a2.y += bb.y; a2.z += bb.z; a2.w += bb.w;
            a3.x += bb.x; a3.y += bb.y; a3.z += bb.z; a3.w += bb.w;
            *(float4*)&y[(m0 + r0 + 0) * V + n0] = a0;
            *(float4*)&y[(m0 + r0 + 1) * V + n0] = a1;
            *(float4*)&y[(m0 + r0 + 2) * V + n0] = a2;
            *(float4*)&y[(m0 + r0 + 3) * V + n0] = a3;
        }
    }
}

// ---------------- launch ----------------
extern "C" void kernel_launch(void* const* d_in, const int* in_sizes, int n_in,
                              void* d_out, int out_size, void* d_ws, size_t ws_size,
                              hipStream_t stream) {
    const int*   X    = (const int*)  d_in[0];
    const float* H1in = (const float*)d_in[1];
    const float* C1in = (const float*)d_in[2];
    const float* H2in = (const float*)d_in[3];
    const float* C2in = (const float*)d_in[4];
    const float* W1f = (const float*)d_in[5];  const float* b1f = (const float*)d_in[6];
    const float* W1i = (const float*)d_in[7];  const float* b1i = (const float*)d_in[8];
    const float* W1o = (const float*)d_in[9];  const float* b1o = (const float*)d_in[10];
    const float* W1c = (const float*)d_in[11]; const float* b1c = (const float*)d_in[12];
    const float* W2f = (const float*)d_in[13]; const float* b2f = (const float*)d_in[14];
    const float* W2i = (const float*)d_in[15]; const float* b2i = (const float*)d_in[16];
    const float* W2o = (const float*)d_in[17]; const float* b2o = (const float*)d_in[18];
    const float* W2c = (const float*)d_in[19]; const float* b2c = (const float*)d_in[20];
    const float* Wout = (const float*)d_in[21]; const float* bout = (const float*)d_in[22];

    float* y   = (float*)d_out;
    float* H1t = y + YSZ;
    float* c1  = y + YSZ + 1 * 32768;   // C1 tail, updated in place
    float* H2t = y + YSZ + 2 * 32768;
    float* c2  = y + YSZ + 3 * 32768;   // C2 tail

    k_init<<<128, 256, 0, stream>>>(C1in, C2in, c1, c2);

    k_cell1_first<<<256, 256, 0, stream>>>(X, H1in, c1,
        W1f, b1f, W1i, b1i, W1o, b1o, W1c, b1c, y + NH);

    for (int t = 0; t < T - 1; ++t) {
        const float* h2p = (t == 0) ? H2in : (y + (size_t)(t - 1) * B * V);
        int h2s = (t == 0) ? NH : V;
        k_step<<<512, 256, 0, stream>>>(t, X, h2p, h2s, y, c1, c2,
            W1f, b1f, W1i, b1i, W1o, b1o, W1c, b1c,
            W2f, b2f, W2i, b2i, W2o, b2o, W2c, b2c);
    }

    k_cell2_last<<<256, 256, 0, stream>>>(
        y + (size_t)(T - 1) * B * V + NH,
        y + (size_t)(T - 2) * B * V,
        c2, W2f, b2f, W2i, b2i, W2o, b2o, W2c, b2c,
        y + (size_t)(T - 1) * B * V);

    k_states<<<128, 256, 0, stream>>>(y, H1t, H2t);

    k_ygemm<<<2048, 256, 0, stream>>>(y, Wout, bout);
}

// Round 2
// 6429.365 us; speedup vs baseline: 2.1441x; 2.1441x over previous
//
#include <hip/hip_runtime.h>
#include <math.h>

static constexpr int V  = 1024;
static constexpr int NH = 256;
static constexpr int B  = 128;
static constexpr int T  = 512;
static constexpr size_t BV  = (size_t)B * V;
static constexpr size_t YSZ = (size_t)T * B * V;   // 67,108,864

typedef _Float16 h8 __attribute__((ext_vector_type(8)));
typedef float f32x4 __attribute__((ext_vector_type(4)));

#define MFMA16(a, b, c) __builtin_amdgcn_mfma_f32_16x16x32_f16((a), (b), (c), 0, 0, 0)

// ---------------------------------------------------------------------------
// Split-f16 scheme: x = hi + lo * 2^-11, with lo stored pre-scaled by 2048 so
// it stays in f16 normal range. Dot products: hi*hi + (hi*lo + lo*hi) * 2^-11.
// ---------------------------------------------------------------------------

// d_out layout (f32): y[T*B][V], then tails: H1[B][NH], C1, H2, C2.
// Recurrence stashes (all inside y, overwritten later by k_ygemm2):
//   h2(t) -> y[t][0:256]      h1(t) -> y[t][256:512]
// c1/c2 live in the C1/C2 tail slots, updated in place.
//
// d_ws layout:
//   pk2  : half[2][64][16][64][8]  = 1,048,576 halves (cell2 weights, K=512)
//   pk1  : half[2][64][ 8][64][8]  =   524,288 halves (cell1 recurrent, K=256)
//   pkY  : half[2][64][ 8][64][8]  =   524,288 halves (Wout, K=256)
//   bp2  : float[1024], bp1 : float[1024]   (gate-interleaved biases)
// pack index: [split][grp][kb][lane][i], n = grp*16 + (lane&15),
//             k = kb*32 + (lane>>4)*8 + i, n = (j<<2)|gate for cells.

__global__ __launch_bounds__(256) void k_prep(
    const float* __restrict__ W1f, const float* __restrict__ W1i,
    const float* __restrict__ W1o, const float* __restrict__ W1c,
    const float* __restrict__ W2f, const float* __restrict__ W2i,
    const float* __restrict__ W2o, const float* __restrict__ W2c,
    const float* __restrict__ Wout,
    const float* __restrict__ b1f, const float* __restrict__ b1i,
    const float* __restrict__ b1o, const float* __restrict__ b1c,
    const float* __restrict__ b2f, const float* __restrict__ b2i,
    const float* __restrict__ b2o, const float* __restrict__ b2c,
    _Float16* __restrict__ pk2, _Float16* __restrict__ pk1,
    _Float16* __restrict__ pkY, float* __restrict__ bp2, float* __restrict__ bp1)
{
    int idx = blockIdx.x * 256 + threadIdx.x;
    if (idx < 2097152) {
        int KB, e, rowoff = 0;
        bool vocabN = false;
        _Float16* dst;
        if (idx < 1048576)      { e = idx;            KB = 16; dst = pk2; }
        else if (idx < 1572864) { e = idx - 1048576;  KB = 8;  dst = pk1; rowoff = V; }
        else                    { e = idx - 1572864;  KB = 8;  dst = pkY; vocabN = true; }
        int S = 64 * KB * 512;
        int split = e / S, r = e % S;
        int grp = r / (KB * 512);
        int r2  = r % (KB * 512);
        int kb = r2 >> 9, lane = (r2 >> 3) & 63, i = r2 & 7;
        int n = grp * 16 + (lane & 15);
        int k = kb * 32 + (lane >> 4) * 8 + i;
        float val;
        if (vocabN) {
            val = Wout[(size_t)k * 1024 + n];
        } else {
            int j = n >> 2, g = n & 3;
            const float* W = (KB == 16)
                ? (g == 0 ? W2f : g == 1 ? W2i : g == 2 ? W2o : W2c)
                : (g == 0 ? W1f : g == 1 ? W1i : g == 2 ? W1o : W1c);
            val = W[(size_t)(rowoff + k) * NH + j];
        }
        _Float16 hi = (_Float16)val;
        dst[e] = split ? (_Float16)((val - (float)hi) * 2048.0f) : hi;
    } else {
        int bi = idx - 2097152;
        if (bi < 1024) {
            int j = bi >> 2, g = bi & 3;
            bp2[bi] = (g == 0 ? b2f : g == 1 ? b2i : g == 2 ? b2o : b2c)[j];
        } else if (bi < 2048) {
            int b2_ = bi - 1024;
            int j = b2_ >> 2, g = b2_ & 3;
            bp1[b2_] = (g == 0 ? b1f : g == 1 ? b1i : g == 2 ? b1o : b1c)[j];
        }
    }
}

__global__ __launch_bounds__(256) void k_init(
    const float* __restrict__ C1in, const float* __restrict__ C2in,
    float* __restrict__ c1, float* __restrict__ c2)
{
    int i = blockIdx.x * 256 + threadIdx.x;   // 32768
    c1[i] = C1in[i];
    c2[i] = C2in[i];
}

// One launch computes cell2(t2) [blocks 0..127] and cell1(t1) [blocks 128..255].
// t<0 disables that half. Each block: 16 batch rows x 64 gate-cols (16 hidden).
__global__ __launch_bounds__(256) void k_cells(
    int t2, int t1,
    const float* __restrict__ h1p, int h1s,     // h1(t) rows, stride h1s
    const float* __restrict__ h2p, int h2s,     // h2(t-1) rows
    const int* __restrict__ X,
    float* __restrict__ y,
    float* __restrict__ c1, float* __restrict__ c2,
    float* __restrict__ H1t, float* __restrict__ H2t,
    const _Float16* __restrict__ pk2, const _Float16* __restrict__ pk1,
    const float* __restrict__ bp2, const float* __restrict__ bp1,
    const float* __restrict__ W1f, const float* __restrict__ W1i,
    const float* __restrict__ W1o, const float* __restrict__ W1c)
{
    const int bid = blockIdx.x, tid = threadIdx.x;
    const bool isC2 = bid < 128;
    if (isC2 ? (t2 < 0) : (t1 < 0)) return;
    const int mp = (bid & 127) >> 4;    // 0..7  (16-row batch slice)
    const int np = bid & 15;            // 0..15 (64 gate-col slice)
    const int r0 = mp * 16;

    __shared__ _Float16 Ah[16][520];    // row stride 1040B = 65*16B -> even bank spread
    __shared__ _Float16 Al[16][520];
    __shared__ float    pre[16][64];

    if (isC2) {
        for (int idx = tid; idx < 16 * 512; idx += 256) {
            int r = idx >> 9, k = idx & 511;
            float v = (k < 256) ? h1p[(size_t)(r0 + r) * h1s + k]
                                : h2p[(size_t)(r0 + r) * h2s + (k - 256)];
            _Float16 hi = (_Float16)v;
            Ah[r][k] = hi;
            Al[r][k] = (_Float16)((v - (float)hi) * 2048.0f);
        }
    } else {
        for (int idx = tid; idx < 16 * 256; idx += 256) {
            int r = idx >> 8, k = idx & 255;
            float v = h1p[(size_t)(r0 + r) * h1s + k];
            _Float16 hi = (_Float16)v;
            Ah[r][k] = hi;
            Al[r][k] = (_Float16)((v - (float)hi) * 2048.0f);
        }
    }
    __syncthreads();

    const int wave = tid >> 6, lane = tid & 63;
    const int col = lane & 15, kg = lane >> 4;
    const int KB = isC2 ? 16 : 8;
    const int ngrp = np * 4 + wave;                 // 16-col group in [0,64)
    const _Float16* pk = isC2 ? pk2 : pk1;
    const size_t so = (size_t)64 * KB * 512;        // split offset (halves)
    const _Float16* pB = pk + ((size_t)ngrp * KB * 64 + lane) * 8;

    f32x4 a0 = {0.f, 0.f, 0.f, 0.f}, a1 = a0, a2 = a0;
    const _Float16* arow_h = &Ah[col][kg * 8];
    const _Float16* arow_l = &Al[col][kg * 8];
    for (int kb = 0; kb < KB; ++kb) {
        h8 ah = *(const h8*)(arow_h + kb * 32);
        h8 al = *(const h8*)(arow_l + kb * 32);
        h8 bh = *(const h8*)(pB + (size_t)kb * 512);
        h8 bl = *(const h8*)(pB + so + (size_t)kb * 512);
        a0 = MFMA16(ah, bh, a0);
        a1 = MFMA16(ah, bl, a1);
        a2 = MFMA16(al, bh, a2);
    }
    const int n_local = wave * 16 + col;
    #pragma unroll
    for (int q = 0; q < 4; ++q)
        pre[kg * 4 + q][n_local] = a0[q] + (a1[q] + a2[q]) * (1.0f / 2048.0f);
    __syncthreads();

    // combine 4 gates per (row, hidden j)
    {
        int r  = tid >> 4, jl = tid & 15;
        float4 g = *(const float4*)&pre[r][jl * 4];
        float4 bb = *(const float4*)&((isC2 ? bp2 : bp1)[np * 64 + jl * 4]);
        float pf = g.x + bb.x, pi = g.y + bb.y, po = g.z + bb.z, pc = g.w + bb.w;
        int b  = r0 + r;
        int jg = np * 16 + jl;
        if (!isC2) {
            int tok = X[b * T + t1];
            pf += W1f[(size_t)tok * NH + jg];
            pi += W1i[(size_t)tok * NH + jg];
            po += W1o[(size_t)tok * NH + jg];
            pc += W1c[(size_t)tok * NH + jg];
        }
        float fg = 1.f / (1.f + expf(-pf));
        float ig = 1.f / (1.f + expf(-pi));
        float og = 1.f / (1.f + expf(-po));
        float ct = tanhf(pc);
        float* cc = isC2 ? c2 : c1;
        float cold = cc[b * NH + jg];
        float cn = fmaf(fg, cold, ig * ct);
        cc[b * NH + jg] = cn;
        float h = og * tanhf(cn);
        if (isC2) {
            y[(size_t)t2 * BV + (size_t)b * V + jg] = h;          // h2 stash
            if (t2 == T - 1) H2t[b * NH + jg] = h;
        } else {
            y[(size_t)t1 * BV + (size_t)b * V + 256 + jg] = h;    // h1 stash
            if (t1 == T - 1) H1t[b * NH + jg] = h;
        }
    }
}

// Y = H2_all @ Wout + bout, in place. Block = 64 rows x ALL 1024 cols
// (stages its rows' h2 into LDS before any write -> race-free in place).
__global__ __launch_bounds__(256) void k_ygemm2(
    float* __restrict__ y, const _Float16* __restrict__ pkY,
    const float* __restrict__ bout)
{
    __shared__ _Float16 Ah[64][264];   // 528B stride -> even bank spread
    __shared__ _Float16 Al[64][264];
    const size_t m0 = (size_t)blockIdx.x * 64;
    const int tid = threadIdx.x;
    for (int idx = tid; idx < 64 * 256; idx += 256) {
        int r = idx >> 8, k = idx & 255;
        float v = y[(m0 + r) * 1024 + k];
        _Float16 hi = (_Float16)v;
        Ah[r][k] = hi;
        Al[r][k] = (_Float16)((v - (float)hi) * 2048.0f);
    }
    __syncthreads();
    const int wave = tid >> 6, lane = tid & 63;
    const int col = lane & 15, kg = lane >> 4;
    const int ar = wave * 16 + col;
    const size_t orow = m0 + wave * 16 + kg * 4;
    for (int npass = 0; npass < 8; ++npass) {
        f32x4 aA[8], aB[8];
        #pragma unroll
        for (int nt = 0; nt < 8; ++nt) { aA[nt] = (f32x4){0.f,0.f,0.f,0.f}; aB[nt] = aA[nt]; }
        for (int kb = 0; kb < 8; ++kb) {
            h8 ah = *(const h8*)&Ah[ar][kb * 32 + kg * 8];
            h8 al = *(const h8*)&Al[ar][kb * 32 + kg * 8];
            #pragma unroll
            for (int nt = 0; nt < 8; ++nt) {
                const int ngrp = npass * 8 + nt;
                const _Float16* pb = pkY + ((size_t)(ngrp * 8 + kb) * 64 + lane) * 8;
                h8 bh = *(const h8*)pb;
                h8 bl = *(const h8*)(pb + 262144);
                aA[nt] = MFMA16(ah, bh, aA[nt]);
                aB[nt] = MFMA16(ah, bl, aB[nt]);
                aB[nt] = MFMA16(al, bh, aB[nt]);
            }
        }
        #pragma unroll
        for (int nt = 0; nt < 8; ++nt) {
            int n = npass * 128 + nt * 16 + col;
            float bb = bout[n];
            #pragma unroll
            for (int q = 0; q < 4; ++q)
                y[(orow + q) * 1024 + n] = aA[nt][q] + aB[nt][q] * (1.0f / 2048.0f) + bb;
        }
    }
}

// ---------------- launch ----------------
extern "C" void kernel_launch(void* const* d_in, const int* in_sizes, int n_in,
                              void* d_out, int out_size, void* d_ws, size_t ws_size,
                              hipStream_t stream) {
    const int*   X    = (const int*)  d_in[0];
    const float* H1in = (const float*)d_in[1];
    const float* C1in = (const float*)d_in[2];
    const float* H2in = (const float*)d_in[3];
    const float* C2in = (const float*)d_in[4];
    const float* W1f = (const float*)d_in[5];  const float* b1f = (const float*)d_in[6];
    const float* W1i = (const float*)d_in[7];  const float* b1i = (const float*)d_in[8];
    const float* W1o = (const float*)d_in[9];  const float* b1o = (const float*)d_in[10];
    const float* W1c = (const float*)d_in[11]; const float* b1c = (const float*)d_in[12];
    const float* W2f = (const float*)d_in[13]; const float* b2f = (const float*)d_in[14];
    const float* W2i = (const float*)d_in[15]; const float* b2i = (const float*)d_in[16];
    const float* W2o = (const float*)d_in[17]; const float* b2o = (const float*)d_in[18];
    const float* W2c = (const float*)d_in[19]; const float* b2c = (const float*)d_in[20];
    const float* Wout = (const float*)d_in[21]; const float* bout = (const float*)d_in[22];

    float* y   = (float*)d_out;
    float* H1t = y + YSZ;
    float* c1  = y + YSZ + 1 * 32768;
    float* H2t = y + YSZ + 2 * 32768;
    float* c2  = y + YSZ + 3 * 32768;

    char* ws = (char*)d_ws;
    _Float16* pk2 = (_Float16*)ws;
    _Float16* pk1 = pk2 + 1048576;
    _Float16* pkY = pk1 + 524288;
    float* bp2 = (float*)(ws + 4194304);
    float* bp1 = bp2 + 1024;

    k_prep<<<8200, 256, 0, stream>>>(W1f, W1i, W1o, W1c, W2f, W2i, W2o, W2c, Wout,
                                     b1f, b1i, b1o, b1c, b2f, b2i, b2o, b2c,
                                     pk2, pk1, pkY, bp2, bp1);
    k_init<<<128, 256, 0, stream>>>(C1in, C2in, c1, c2);

    // cell1(0) from H1in
    k_cells<<<256, 256, 0, stream>>>(-1, 0, H1in, NH, H2in, NH, X, y, c1, c2,
                                     H1t, H2t, pk2, pk1, bp2, bp1, W1f, W1i, W1o, W1c);
    // steps: cell2(t) + cell1(t+1)
    for (int t = 0; t <= 510; ++t) {
        const float* h1p = y + (size_t)t * BV + 256;
        const float* h2p = (t == 0) ? H2in : (y + (size_t)(t - 1) * BV);
        int h2s = (t == 0) ? NH : (int)V;
        k_cells<<<256, 256, 0, stream>>>(t, t + 1, h1p, V, h2p, h2s, X, y, c1, c2,
                                         H1t, H2t, pk2, pk1, bp2, bp1, W1f, W1i, W1o, W1c);
    }
    // final cell2(511)
    k_cells<<<256, 256, 0, stream>>>(511, -1, y + (size_t)511 * BV + 256, V,
                                     y + (size_t)510 * BV, V, X, y, c1, c2,
                                     H1t, H2t, pk2, pk1, bp2, bp1, W1f, W1i, W1o, W1c);

    k_ygemm2<<<1024, 256, 0, stream>>>(y, pkY, bout);
}